// Round 18
// baseline (163.870 us; speedup 1.0000x reference)
//
#include <hip/hip_runtime.h>

#define HIMG 192
#define HWSZ (192*192)
#define NWX  24

typedef __bf16 bf16;
typedef __bf16 bf16x2 __attribute__((ext_vector_type(2)));
typedef __bf16 bf16x4 __attribute__((ext_vector_type(4)));
typedef __bf16 bf16x8 __attribute__((ext_vector_type(8)));
typedef float  f32x4  __attribute__((ext_vector_type(4)));

#define MFMA(a,b,c) __builtin_amdgcn_mfma_f32_16x16x32_bf16((a),(b),(c),0,0,0)
#define SW(r) (((((r)&7) ^ ((((r)>>3)&1)<<2))) << 4)

static __device__ __forceinline__ bf16x8 ldg8(const float* p) {
    const float4 u = ((const float4*)p)[0];
    const float4 v = ((const float4*)p)[1];
    bf16x8 r;
    r[0]=(bf16)u.x; r[1]=(bf16)u.y; r[2]=(bf16)u.z; r[3]=(bf16)u.w;
    r[4]=(bf16)v.x; r[5]=(bf16)v.y; r[6]=(bf16)v.z; r[7]=(bf16)v.w;
    return r;
}
template<int WSB>
static __device__ __forceinline__ bf16x8 ldw(const float* wf, const bf16* wh, int off) {
    if (WSB) return *(const bf16x8*)(wh + off);
    return ldg8(wf + off);
}
static __device__ __forceinline__ bf16x4 pk4b(f32x4 v, float4 b) {
    bf16x4 r; r[0]=(bf16)(v[0]+b.x); r[1]=(bf16)(v[1]+b.y);
    r[2]=(bf16)(v[2]+b.z); r[3]=(bf16)(v[3]+b.w); return r;
}
static __device__ __forceinline__ bf16x4 pk4bs(f32x4 v, float4 b, float s) {
    bf16x4 r; r[0]=(bf16)((v[0]+b.x)*s); r[1]=(bf16)((v[1]+b.y)*s);
    r[2]=(bf16)((v[2]+b.z)*s); r[3]=(bf16)((v[3]+b.w)*s); return r;
}
static __device__ __forceinline__ bf16x4 pk4c(f32x4 v, float b) {
    bf16x4 r; r[0]=(bf16)(v[0]+b); r[1]=(bf16)(v[1]+b);
    r[2]=(bf16)(v[2]+b); r[3]=(bf16)(v[3]+b); return r;
}
static __device__ __forceinline__ bf16x4 pk4s(f32x4 v, float s) {
    bf16x4 r; r[0]=(bf16)(v[0]*s); r[1]=(bf16)(v[1]*s);
    r[2]=(bf16)(v[2]*s); r[3]=(bf16)(v[3]*s); return r;
}
static __device__ __forceinline__ bf16x4 pk4(f32x4 v) {
    bf16x4 r; r[0]=(bf16)v[0]; r[1]=(bf16)v[1]; r[2]=(bf16)v[2]; r[3]=(bf16)v[3]; return r;
}
static __device__ __forceinline__ bf16x8 cat8(bf16x4 a, bf16x4 b) {
    bf16x8 r; r[0]=a[0]; r[1]=a[1]; r[2]=a[2]; r[3]=a[3];
    r[4]=b[0]; r[5]=b[1]; r[6]=b[2]; r[7]=b[3]; return r;
}
static __device__ __forceinline__ f32x4 splat4(float b) {
    f32x4 r; r[0]=b; r[1]=b; r[2]=b; r[3]=b; return r;
}
static __device__ __forceinline__ f32x4 f4of(float4 b) {
    f32x4 r; r[0]=b.x; r[1]=b.y; r[2]=b.z; r[3]=b.w; return r;
}
static __device__ __forceinline__ f32x4 f4ofs(float4 b, float s) {
    f32x4 r; r[0]=b.x*s; r[1]=b.y*s; r[2]=b.z*s; r[3]=b.w*s; return r;
}

// ---------------------------------------------------------------------------
// Setup: parameter tables incl. frag-layout (lane-coalesced) copies.
// hqkvf Q-section is pre-scaled by 32^-0.5.
// ---------------------------------------------------------------------------
__global__ __launch_bounds__(256) void setup_ws(const float* __restrict__ rpb,
                                                const float* __restrict__ qkv_w,
                                                const float* __restrict__ proj_w,
                                                float* __restrict__ wbias,
                                                bf16* __restrict__ hqkv,
                                                bf16* __restrict__ hproj,
                                                float* __restrict__ wbf,
                                                bf16* __restrict__ hqkvf,
                                                bf16* __restrict__ hprojf) {
    const int e = blockIdx.x * 256 + threadIdx.x;   // 0..163839
    if (e < 16384) {
        const int h = e >> 12, i = (e >> 6) & 63, j = e & 63;
        const int dy = (i >> 3) - (j >> 3) + 7;
        const int dx = (i & 7)  - (j & 7)  + 7;
        wbias[e] = rpb[(dy * 15 + dx) * 4 + h];
    } else if (e < 65536) {
        const int i = e - 16384;
        hqkv[i] = (bf16)qkv_w[i];
    } else if (e < 81920) {
        const int i = e - 65536;
        hproj[i] = (bf16)proj_w[i];
    } else if (e < 98304) {
        const int t = e - 81920;
        const int r = t & 3, lane = (t >> 2) & 63;
        const int m = (t >> 8) & 3, n = (t >> 10) & 3, h = t >> 12;
        const int lo = lane & 15, hi = lane >> 4;
        const int i_ = n*16 + lo;
        const int j_ = (m >> 1)*32 + hi*8 + (m & 1)*4 + r;
        const int dy = (i_ >> 3) - (j_ >> 3) + 7;
        const int dx = (i_ & 7)  - (j_ & 7)  + 7;
        wbf[t] = rpb[(dy * 15 + dx) * 4 + h];
    } else if (e < 147456) {
        const int t = e - 98304;
        const int el = t & 7, lane = (t >> 3) & 63;
        const int a = (t >> 9) & 1, kb = (t >> 10) & 3;
        const int h = (t >> 12) & 3, ph = t >> 14;
        const int lo = lane & 15, hi = lane >> 4;
        const int prow = ((lo >> 2) << 3) + (lo & 3);
        const int row = (ph == 2) ? (256 + h*32 + a*16 + lo)
                                  : (ph*128 + h*32 + prow + a*4);
        const int col = kb*32 + hi*8 + el;
        float wv_ = qkv_w[row*128 + col];
        if (ph == 0) wv_ *= 0.17677669529663687f;   // fold attention scale into Wq
        hqkvf[t] = (bf16)wv_;
    } else {
        const int t = e - 147456;
        const int el = t & 7, lane = (t >> 3) & 63;
        const int tA = (t >> 9) & 3, kb = (t >> 11) & 3, oh = t >> 13;
        const int lo = lane & 15, hi = lane >> 4;
        const int row = oh*64 + tA*16 + lo;
        const int col = kb*32 + hi*8 + el;
        hprojf[t] = (bf16)proj_w[row*128 + col];
    }
}

// ---------------------------------------------------------------------------
// Fused gather + QKV + attention, register-slimmed phases:
//   gather -> Q -> K -> S+softmax(pf) -> V(both halves, one xf pass) -> PV.
// Peak accumulator live-set <= 32 per phase -> fits __launch_bounds__(256,4)
// (verified no-spill in round 17); single xf pass in V restores the lower
// LDS-read count / bank-conflict level of round 16.
// Trims: biases as MFMA C-init, SCALE folded into Wq, no-max-sub softmax.
// ---------------------------------------------------------------------------
__global__ __launch_bounds__(256, 4)
void qkv_attn(const float* __restrict__ x, const float* __restrict__ qkv_b,
              const bf16* __restrict__ hqkvf, const float* __restrict__ wbf,
              bf16* __restrict__ obuf)
{
    __shared__ char sX[16384];   // [64 tok][256B ch] bf16, col ^ SW(tok)
    const int tid  = threadIdx.x;
    const int lane = tid & 63;
    const int h    = tid >> 6;
    const int lo   = lane & 15;
    const int hi   = lane >> 4;

    const int bid   = blockIdx.x;        // == win index
    const int batch = bid & 7;
    const int wrem  = bid >> 3;
    const int wy    = wrem / NWX;
    const int wx    = wrem - wy * NWX;

    const float SCALE = 0.17677669529663687f;
    const int prow = ((lo >> 2) << 3) + (lo & 3);

    // ---- gather+roll -> LDS: 512 (chq,row,w4) tiles, 4 planes per tile ----
    {
        const int hbase = wy*8 + 4;
        const int wbase = wx*8 + 4;
        #pragma unroll
        for (int k = 0; k < 2; ++k) {
            const int id  = k*256 + tid;     // 0..511
            const int w4  = id & 1;
            const int row = (id >> 1) & 7;
            const int chq = id >> 4;         // channel quad 0..31
            int hh = hbase + row;  if (hh >= HIMG) hh -= HIMG;
            int ww = wbase + w4*4; if (ww >= HIMG) ww -= HIMG;
            const float* p0 = x + (size_t)(batch*128 + chq*4) * HWSZ + hh*HIMG + ww;
            const float4 a = *(const float4*)p0;
            const float4 b = *(const float4*)(p0 + HWSZ);
            const float4 c = *(const float4*)(p0 + 2*HWSZ);
            const float4 d = *(const float4*)(p0 + 3*HWSZ);
            const int t0 = row*8 + w4*4;
            #pragma unroll
            for (int e = 0; e < 4; ++e) {
                const int t = t0 + e;
                bf16x4 pr;
                pr[0] = (bf16)(&a.x)[e]; pr[1] = (bf16)(&b.x)[e];
                pr[2] = (bf16)(&c.x)[e]; pr[3] = (bf16)(&d.x)[e];
                *(bf16x4*)(sX + t*256 + ((8*chq) ^ SW(t))) = pr;
            }
        }
    }
    __syncthreads();   // only barrier

    const bf16* const wQ = hqkvf + h * 4096;            // pre-scaled
    const bf16* const wK = hqkvf + 16384 + h * 4096;
    const bf16* const wV = hqkvf + 32768 + h * 4096;

    bf16x8 qf[4], kf[4];

    // ---- Q^T = (S*Wq) @ X^T, bias via C-init ----
    {
        const float4 b0 = *(const float4*)(qkv_b + h*32 + hi*8);
        const float4 b1 = *(const float4*)(qkv_b + h*32 + hi*8 + 4);
        const f32x4 c0 = f4ofs(b0, SCALE);
        const f32x4 c1 = f4ofs(b1, SCALE);
        f32x4 acc[2][4];
        #pragma unroll
        for (int n = 0; n < 4; ++n) { acc[0][n] = c0; acc[1][n] = c1; }
        #pragma unroll
        for (int kb = 0; kb < 4; ++kb) {
            bf16x8 xf[4];
            #pragma unroll
            for (int n = 0; n < 4; ++n) {
                const int row = n*16 + lo;
                xf[n] = *(const bf16x8*)(sX + row*256 + ((kb*64 + hi*16) ^ SW(row)));
            }
            const bf16x8 w0 = *(const bf16x8*)(wQ + (kb*2    )*512 + lane*8);
            const bf16x8 w1 = *(const bf16x8*)(wQ + (kb*2 + 1)*512 + lane*8);
            #pragma unroll
            for (int n = 0; n < 4; ++n) {
                acc[0][n] = MFMA(w0, xf[n], acc[0][n]);
                acc[1][n] = MFMA(w1, xf[n], acc[1][n]);
            }
        }
        #pragma unroll
        for (int n = 0; n < 4; ++n)
            qf[n] = cat8(pk4(acc[0][n]), pk4(acc[1][n]));
    }

    // ---- K^T only (A-frags, token-permuted rows), bias via C-init ----
    {
        const float4 k0 = *(const float4*)(qkv_b + 128 + h*32 + hi*8);
        const float4 k1 = *(const float4*)(qkv_b + 128 + h*32 + hi*8 + 4);
        const f32x4 ck0 = f4of(k0), ck1 = f4of(k1);
        f32x4 ak[2][4];
        #pragma unroll
        for (int m = 0; m < 4; ++m) { ak[0][m] = ck0; ak[1][m] = ck1; }
        #pragma unroll
        for (int kb = 0; kb < 4; ++kb) {
            bf16x8 xf[4];
            #pragma unroll
            for (int m = 0; m < 4; ++m) {
                const int row = (m >> 1)*32 + (m & 1)*4 + prow;
                xf[m] = *(const bf16x8*)(sX + row*256 + ((kb*64 + hi*16) ^ SW(row)));
            }
            const bf16x8 wk0 = *(const bf16x8*)(wK + (kb*2    )*512 + lane*8);
            const bf16x8 wk1 = *(const bf16x8*)(wK + (kb*2 + 1)*512 + lane*8);
            #pragma unroll
            for (int m = 0; m < 4; ++m) {
                ak[0][m] = MFMA(wk0, xf[m], ak[0][m]);
                ak[1][m] = MFMA(wk1, xf[m], ak[1][m]);
            }
        }
        #pragma unroll
        for (int m = 0; m < 4; ++m)
            kf[m] = cat8(pk4(ak[0][m]), pk4(ak[1][m]));
    }

    // ---- S^T = K @ Q^T + (bias+mask as C-init); softmax (no max-sub) ----
    const bool ey = (wy == 23), ex = (wx == 23);
    const bool edge = ey || ex;
    const float* const wbh = wbf + h * 4096;
    bf16x8 pf[2][4];
    float rinv[4];
    #pragma unroll
    for (int n = 0; n < 4; ++n) {
        const int i_ = n*16 + lo;
        const int yi = i_ >> 3, xi = i_ & 7;
        const int ri = (ey ? (yi < 4 ? 1 : 2) : 0) * 3 + (ex ? (xi < 4 ? 1 : 2) : 0);
        f32x4 sc[4];
        #pragma unroll
        for (int m = 0; m < 4; ++m) {
            f32x4 ci = *(const f32x4*)(wbh + (n*4 + m)*256 + lane*4);
            if (edge) {
                #pragma unroll
                for (int r = 0; r < 4; ++r) {
                    const int j_ = (m >> 1)*32 + hi*8 + (m & 1)*4 + r;
                    const int yj = j_ >> 3, xj = j_ & 7;
                    const int rj = (ey ? (yj < 4 ? 1 : 2) : 0) * 3 + (ex ? (xj < 4 ? 1 : 2) : 0);
                    ci[r] += (ri != rj) ? -100.0f : 0.0f;
                }
            }
            sc[m] = MFMA(kf[m], qf[n], ci);
        }
        float sum = 0.f;
        #pragma unroll
        for (int m = 0; m < 4; ++m)
            #pragma unroll
            for (int r = 0; r < 4; ++r) {
                const float p = __expf(sc[m][r]);
                sc[m][r] = p; sum += p;
            }
        sum += __shfl_xor(sum, 16);
        sum += __shfl_xor(sum, 32);
        rinv[n] = 1.0f / sum;
        pf[0][n] = cat8(pk4(sc[0]), pk4(sc[1]));
        pf[1][n] = cat8(pk4(sc[2]), pk4(sc[3]));
    }

    // ---- V (both o-halves, single xf pass), bias via C-init ----
    bf16x8 vf[2][2];   // vf[o][kb2]
    {
        const float bv0 = qkv_b[256 + h*32 + lo];
        const float bv1 = qkv_b[256 + h*32 + 16 + lo];
        const f32x4 cv0 = splat4(bv0), cv1 = splat4(bv1);
        f32x4 av[4][2];
        #pragma unroll
        for (int m = 0; m < 4; ++m) { av[m][0] = cv0; av[m][1] = cv1; }
        #pragma unroll
        for (int kb = 0; kb < 4; ++kb) {
            bf16x8 xf[4];
            #pragma unroll
            for (int m = 0; m < 4; ++m) {
                const int row = (m >> 1)*32 + (m & 1)*4 + prow;
                xf[m] = *(const bf16x8*)(sX + row*256 + ((kb*64 + hi*16) ^ SW(row)));
            }
            const bf16x8 wv0 = *(const bf16x8*)(wV + (kb*2    )*512 + lane*8);
            const bf16x8 wv1 = *(const bf16x8*)(wV + (kb*2 + 1)*512 + lane*8);
            #pragma unroll
            for (int m = 0; m < 4; ++m) {
                av[m][0] = MFMA(xf[m], wv0, av[m][0]);
                av[m][1] = MFMA(xf[m], wv1, av[m][1]);
            }
        }
        #pragma unroll
        for (int kb = 0; kb < 2; ++kb) {
            vf[0][kb] = cat8(pk4(av[kb*2][0]), pk4(av[kb*2 + 1][0]));
            vf[1][kb] = cat8(pk4(av[kb*2][1]), pk4(av[kb*2 + 1][1]));
        }
    }

    // ---- O^T = V^T @ P^T; coalesced frag store ----
    bf16* const ob = obuf + (size_t)bid * 8192 + h * 2048;
    #pragma unroll
    for (int o = 0; o < 2; ++o) {
        f32x4 o0[4];
        #pragma unroll
        for (int n = 0; n < 4; ++n) { o0[n][0]=0.f; o0[n][1]=0.f; o0[n][2]=0.f; o0[n][3]=0.f; }
        #pragma unroll
        for (int kb = 0; kb < 2; ++kb)
            #pragma unroll
            for (int n = 0; n < 4; ++n)
                o0[n] = MFMA(vf[o][kb], pf[kb][n], o0[n]);
        #pragma unroll
        for (int n = 0; n < 4; ++n)
            *(bf16x4*)(ob + (n*2 + o)*256 + lane*4) = pk4s(o0[n], rinv[n]);
    }
}

// ---------------------------------------------------------------------------
// Projection by image rows (unchanged).
// ---------------------------------------------------------------------------
__global__ __launch_bounds__(512, 3)
void proj_rows(const bf16* __restrict__ obuf, const bf16* __restrict__ hprojf,
               const float* __restrict__ proj_b, float* __restrict__ out)
{
    __shared__ char sR[49152];   // [192 tok][256B bf16], col ^ SW(tok)
    const int tid  = threadIdx.x;
    const int lane = tid & 63;
    const int wv   = tid >> 6;
    const int lo   = lane & 15;
    const int hi   = lane >> 4;

    const int bid   = blockIdx.x;        // 1536 = 8 batch x 192 rows
    const int batch = bid & 7;
    const int hh    = bid >> 3;          // output row 0..191
    int hr = hh + 188; if (hr >= 192) hr -= 192;   // rolled-frame row
    const int wy = hr >> 3, iy = hr & 7;
    const int n_ = iy >> 1;

    #pragma unroll
    for (int k = 0; k < 6; ++k) {
        const int i  = tid + k*512;      // 0..3071
        const int wr = i >> 4;           // rolled-frame col
        const int cc = i & 15;           // 8-channel chunk
        const int wxx = wr >> 3, ix = wr & 7;
        const int win = (wy*NWX + wxx)*8 + batch;
        const int lo2 = (iy & 1)*8 + ix;
        const int hg = cc >> 2, oo = (cc >> 1) & 1, hp = cc & 1;
        const bf16* bp = obuf + (size_t)win*8192 + hg*2048 + (n_*2 + oo)*256;
        const bf16x4 p0 = *(const bf16x4*)(bp + ((hp*2    )*16 + lo2)*4);
        const bf16x4 p1 = *(const bf16x4*)(bp + ((hp*2 + 1)*16 + lo2)*4);
        int wo = wr + 4; if (wo >= 192) wo -= 192;
        *(bf16x8*)(sR + wo*256 + ((cc*16) ^ SW(wo))) = cat8(p0, p1);
    }
    __syncthreads();

    const int q  = wv >> 1;
    const int oh = wv & 1;
    const f32x4 FZ = {0.f, 0.f, 0.f, 0.f};
    f32x4 acc[4][3];
    #pragma unroll
    for (int tA = 0; tA < 4; ++tA)
        #pragma unroll
        for (int tN = 0; tN < 3; ++tN) acc[tA][tN] = FZ;

    #pragma unroll
    for (int kb = 0; kb < 4; ++kb) {
        bf16x8 of[3];
        #pragma unroll
        for (int tN = 0; tN < 3; ++tN) {
            const int tok = q*48 + tN*16 + lo;
            of[tN] = *(const bf16x8*)(sR + tok*256 + ((kb*64 + hi*16) ^ SW(tok)));
        }
        bf16x8 wf[4];
        #pragma unroll
        for (int tA = 0; tA < 4; ++tA)
            wf[tA] = *(const bf16x8*)(hprojf + (size_t)(((oh*4 + kb)*4 + tA)*64 + lane)*8);
        #pragma unroll
        for (int tA = 0; tA < 4; ++tA)
            #pragma unroll
            for (int tN = 0; tN < 3; ++tN)
                acc[tA][tN] = MFMA(of[tN], wf[tA], acc[tA][tN]);
    }

    #pragma unroll
    for (int tA = 0; tA < 4; ++tA) {
        const int oc = oh*64 + tA*16 + lo;
        const float pb = proj_b[oc];
        float* const orow = out + (size_t)(batch*128 + oc) * HWSZ + hh*HIMG;
        #pragma unroll
        for (int tN = 0; tN < 3; ++tN) {
            const int tb = q*48 + tN*16 + hi*4;
            float4 v;
            v.x = acc[tA][tN][0] + pb;
            v.y = acc[tA][tN][1] + pb;
            v.z = acc[tA][tN][2] + pb;
            v.w = acc[tA][tN][3] + pb;
            *(float4*)(orow + tb) = v;
        }
    }
}

// ---------------------------------------------------------------------------
// Fallback: minimal correct path for small workspaces (fp32, simple): one
// thread per (batch, head, token) is too slow but correct; use tiny grid.
// To keep the file compact we reuse qkv-attn pipeline requirements instead:
// fallback computes directly with fp32 math, no workspace.
// ---------------------------------------------------------------------------
__global__ __launch_bounds__(64)
void swin_ref(const float* __restrict__ x, const float* __restrict__ qkv_w,
              const float* __restrict__ qkv_b, const float* __restrict__ proj_w,
              const float* __restrict__ proj_b, const float* __restrict__ rpb,
              float* __restrict__ out)
{
    // grid: 4608 windows x 64 threads (one token each). Straightforward fp32.
    const int bid   = blockIdx.x;
    const int batch = bid & 7;
    const int wrem  = bid >> 3;
    const int wy    = wrem / NWX;
    const int wx    = wrem - wy * NWX;
    const int t     = threadIdx.x;       // token in window
    const int iy = t >> 3, ix = t & 7;
    const bool ey = (wy == 23), ex = (wx == 23);

    __shared__ float sxw[64][128];   // window features
    __shared__ float sq[64][128], sk[64][128], sv[64][128], so[64][128];

    int hh = wy*8 + iy + 4; if (hh >= HIMG) hh -= HIMG;
    int ww = wx*8 + ix + 4; if (ww >= HIMG) ww -= HIMG;
    const float* xp = x + (size_t)batch*128*HWSZ + hh*HIMG + ww;
    for (int c = 0; c < 128; ++c) sxw[t][c] = xp[(size_t)c*HWSZ];
    __syncthreads();

    for (int d = 0; d < 128; ++d) {
        float aq = qkv_b[d], ak2 = qkv_b[128 + d], av2 = qkv_b[256 + d];
        for (int c = 0; c < 128; ++c) {
            const float xv = sxw[t][c];
            aq  += qkv_w[d*128 + c] * xv;
            ak2 += qkv_w[(128 + d)*128 + c] * xv;
            av2 += qkv_w[(256 + d)*128 + c] * xv;
        }
        sq[t][d] = aq; sk[t][d] = ak2; sv[t][d] = av2;
    }
    __syncthreads();

    const float SCALE = 0.17677669529663687f;
    const int ri = (ey ? (iy < 4 ? 1 : 2) : 0) * 3 + (ex ? (ix < 4 ? 1 : 2) : 0);
    for (int h = 0; h < 4; ++h) {
        float p[64];
        float mx = -1e30f;
        for (int j = 0; j < 64; ++j) {
            const int yj = j >> 3, xj = j & 7;
            float s = 0.f;
            for (int d = 0; d < 32; ++d)
                s += sq[t][h*32 + d] * sk[j][h*32 + d];
            s = s * SCALE + rpb[((iy - yj + 7)*15 + (ix - xj + 7))*4 + h];
            const int rj = (ey ? (yj < 4 ? 1 : 2) : 0) * 3 + (ex ? (xj < 4 ? 1 : 2) : 0);
            if (ri != rj) s -= 100.0f;
            p[j] = s; mx = fmaxf(mx, s);
        }
        float sum = 0.f;
        for (int j = 0; j < 64; ++j) { p[j] = __expf(p[j] - mx); sum += p[j]; }
        const float inv = 1.0f / sum;
        for (int d = 0; d < 32; ++d) {
            float o = 0.f;
            for (int j = 0; j < 64; ++j) o += p[j] * sv[j][h*32 + d];
            so[t][h*32 + d] = o * inv;
        }
    }
    __syncthreads();

    for (int d = 0; d < 128; ++d) {
        float a = proj_b[d];
        for (int c = 0; c < 128; ++c) a += proj_w[d*128 + c] * so[t][c];
        out[(size_t)(batch*128 + d)*HWSZ + hh*HIMG + ww] = a;
    }
}

extern "C" void kernel_launch(void* const* d_in, const int* in_sizes, int n_in,
                              void* d_out, int out_size, void* d_ws, size_t ws_size,
                              hipStream_t stream) {
    const float* x      = (const float*)d_in[0];
    const float* qkv_w  = (const float*)d_in[1];
    const float* qkv_b  = (const float*)d_in[2];
    const float* proj_w = (const float*)d_in[3];
    const float* proj_b = (const float*)d_in[4];
    const float* rpb    = (const float*)d_in[5];
    float* out = (float*)d_out;

    // ws bytes: [0,64K) wbias f32 | [64K,160K) hqkv | [160K,192K) hproj
    //           [192K,256K) wbf f32 | [256K,352K) hqkvf | [352K,384K) hprojf
    //           [384K, +75.5M) obuf
    const size_t SETUP = 393216;
    const size_t OSZ   = (size_t)4608 * 16384;

    float* wbias = (float*)d_ws;
    bf16*  hqkv  = (bf16*)((char*)d_ws + 65536);
    bf16*  hproj = (bf16*)((char*)d_ws + 163840);
    float* wbf   = (float*)((char*)d_ws + 196608);
    bf16*  hqkvf = (bf16*)((char*)d_ws + 262144);
    bf16*  hprojf= (bf16*)((char*)d_ws + 360448);
    bf16*  obuf  = (bf16*)((char*)d_ws + SETUP);

    if (ws_size >= SETUP + OSZ) {
        setup_ws<<<640, 256, 0, stream>>>(rpb, qkv_w, proj_w, wbias, hqkv, hproj,
                                          wbf, hqkvf, hprojf);
        qkv_attn<<<4608, 256, 0, stream>>>(x, qkv_b, hqkvf, wbf, obuf);
        proj_rows<<<1536, 512, 0, stream>>>(obuf, hprojf, proj_b, out);
    } else {
        swin_ref<<<4608, 64, 0, stream>>>(x, qkv_w, qkv_b, proj_w, proj_b, rpb, out);
    }
}

// Round 19
// 147.258 us; speedup vs baseline: 1.1128x; 1.1128x over previous
//
#include <hip/hip_runtime.h>

#define HIMG 192
#define HWSZ (192*192)
#define NWX  24

typedef __bf16 bf16;
typedef __bf16 bf16x2 __attribute__((ext_vector_type(2)));
typedef __bf16 bf16x4 __attribute__((ext_vector_type(4)));
typedef __bf16 bf16x8 __attribute__((ext_vector_type(8)));
typedef float  f32x4  __attribute__((ext_vector_type(4)));

#define MFMA(a,b,c) __builtin_amdgcn_mfma_f32_16x16x32_bf16((a),(b),(c),0,0,0)
#define SW(r) (((((r)&7) ^ ((((r)>>3)&1)<<2))) << 4)

static __device__ __forceinline__ bf16x4 pk4s(f32x4 v, float s) {
    bf16x4 r; r[0]=(bf16)(v[0]*s); r[1]=(bf16)(v[1]*s);
    r[2]=(bf16)(v[2]*s); r[3]=(bf16)(v[3]*s); return r;
}
static __device__ __forceinline__ bf16x4 pk4(f32x4 v) {
    bf16x4 r; r[0]=(bf16)v[0]; r[1]=(bf16)v[1]; r[2]=(bf16)v[2]; r[3]=(bf16)v[3]; return r;
}
static __device__ __forceinline__ bf16x8 cat8(bf16x4 a, bf16x4 b) {
    bf16x8 r; r[0]=a[0]; r[1]=a[1]; r[2]=a[2]; r[3]=a[3];
    r[4]=b[0]; r[5]=b[1]; r[6]=b[2]; r[7]=b[3]; return r;
}
static __device__ __forceinline__ f32x4 splat4(float b) {
    f32x4 r; r[0]=b; r[1]=b; r[2]=b; r[3]=b; return r;
}
static __device__ __forceinline__ f32x4 f4of(float4 b) {
    f32x4 r; r[0]=b.x; r[1]=b.y; r[2]=b.z; r[3]=b.w; return r;
}
static __device__ __forceinline__ f32x4 f4ofs(float4 b, float s) {
    f32x4 r; r[0]=b.x*s; r[1]=b.y*s; r[2]=b.z*s; r[3]=b.w*s; return r;
}

// ---------------------------------------------------------------------------
// Setup: parameter tables incl. frag-layout (lane-coalesced) copies.
// hqkvf Q-section is pre-scaled by 32^-0.5.
// ---------------------------------------------------------------------------
__global__ __launch_bounds__(256) void setup_ws(const float* __restrict__ rpb,
                                                const float* __restrict__ qkv_w,
                                                const float* __restrict__ proj_w,
                                                float* __restrict__ wbias,
                                                bf16* __restrict__ hqkv,
                                                bf16* __restrict__ hproj,
                                                float* __restrict__ wbf,
                                                bf16* __restrict__ hqkvf,
                                                bf16* __restrict__ hprojf) {
    const int e = blockIdx.x * 256 + threadIdx.x;   // 0..163839
    if (e < 16384) {
        const int h = e >> 12, i = (e >> 6) & 63, j = e & 63;
        const int dy = (i >> 3) - (j >> 3) + 7;
        const int dx = (i & 7)  - (j & 7)  + 7;
        wbias[e] = rpb[(dy * 15 + dx) * 4 + h];
    } else if (e < 65536) {
        const int i = e - 16384;
        hqkv[i] = (bf16)qkv_w[i];
    } else if (e < 81920) {
        const int i = e - 65536;
        hproj[i] = (bf16)proj_w[i];
    } else if (e < 98304) {
        const int t = e - 81920;
        const int r = t & 3, lane = (t >> 2) & 63;
        const int m = (t >> 8) & 3, n = (t >> 10) & 3, h = t >> 12;
        const int lo = lane & 15, hi = lane >> 4;
        const int i_ = n*16 + lo;
        const int j_ = (m >> 1)*32 + hi*8 + (m & 1)*4 + r;
        const int dy = (i_ >> 3) - (j_ >> 3) + 7;
        const int dx = (i_ & 7)  - (j_ & 7)  + 7;
        wbf[t] = rpb[(dy * 15 + dx) * 4 + h];
    } else if (e < 147456) {
        const int t = e - 98304;
        const int el = t & 7, lane = (t >> 3) & 63;
        const int a = (t >> 9) & 1, kb = (t >> 10) & 3;
        const int h = (t >> 12) & 3, ph = t >> 14;
        const int lo = lane & 15, hi = lane >> 4;
        const int prow = ((lo >> 2) << 3) + (lo & 3);
        const int row = (ph == 2) ? (256 + h*32 + a*16 + lo)
                                  : (ph*128 + h*32 + prow + a*4);
        const int col = kb*32 + hi*8 + el;
        float wv_ = qkv_w[row*128 + col];
        if (ph == 0) wv_ *= 0.17677669529663687f;   // fold attention scale into Wq
        hqkvf[t] = (bf16)wv_;
    } else {
        const int t = e - 147456;
        const int el = t & 7, lane = (t >> 3) & 63;
        const int tA = (t >> 9) & 3, kb = (t >> 11) & 3, oh = t >> 13;
        const int lo = lane & 15, hi = lane >> 4;
        const int row = oh*64 + tA*16 + lo;
        const int col = kb*32 + hi*8 + el;
        hprojf[t] = (bf16)proj_w[row*128 + col];
    }
}

// ---------------------------------------------------------------------------
// Fused gather + QKV + attention (round-17 configuration, confirmed best):
//   gather -> Q -> K -> S+softmax(pf) -> {V fused with PV per o-half}.
// Peak accumulator live-set <= 32 regs per phase -> fits
// __launch_bounds__(256,4) with ZERO spill (verified: WRITE == 74MB exactly).
// Trims: biases as MFMA C-init, SCALE folded into Wq, no-max-sub softmax.
// ---------------------------------------------------------------------------
__global__ __launch_bounds__(256, 4)
void qkv_attn(const float* __restrict__ x, const float* __restrict__ qkv_b,
              const bf16* __restrict__ hqkvf, const float* __restrict__ wbf,
              bf16* __restrict__ obuf)
{
    __shared__ char sX[16384];   // [64 tok][256B ch] bf16, col ^ SW(tok)
    const int tid  = threadIdx.x;
    const int lane = tid & 63;
    const int h    = tid >> 6;
    const int lo   = lane & 15;
    const int hi   = lane >> 4;

    const int bid   = blockIdx.x;        // == win index
    const int batch = bid & 7;
    const int wrem  = bid >> 3;
    const int wy    = wrem / NWX;
    const int wx    = wrem - wy * NWX;

    const float SCALE = 0.17677669529663687f;
    const int prow = ((lo >> 2) << 3) + (lo & 3);

    // ---- gather+roll -> LDS: 512 (chq,row,w4) tiles, 4 planes per tile ----
    {
        const int hbase = wy*8 + 4;
        const int wbase = wx*8 + 4;
        #pragma unroll
        for (int k = 0; k < 2; ++k) {
            const int id  = k*256 + tid;     // 0..511
            const int w4  = id & 1;
            const int row = (id >> 1) & 7;
            const int chq = id >> 4;         // channel quad 0..31
            int hh = hbase + row;  if (hh >= HIMG) hh -= HIMG;
            int ww = wbase + w4*4; if (ww >= HIMG) ww -= HIMG;
            const float* p0 = x + (size_t)(batch*128 + chq*4) * HWSZ + hh*HIMG + ww;
            const float4 a = *(const float4*)p0;
            const float4 b = *(const float4*)(p0 + HWSZ);
            const float4 c = *(const float4*)(p0 + 2*HWSZ);
            const float4 d = *(const float4*)(p0 + 3*HWSZ);
            const int t0 = row*8 + w4*4;
            #pragma unroll
            for (int e = 0; e < 4; ++e) {
                const int t = t0 + e;
                bf16x4 pr;
                pr[0] = (bf16)(&a.x)[e]; pr[1] = (bf16)(&b.x)[e];
                pr[2] = (bf16)(&c.x)[e]; pr[3] = (bf16)(&d.x)[e];
                *(bf16x4*)(sX + t*256 + ((8*chq) ^ SW(t))) = pr;
            }
        }
    }
    __syncthreads();   // only barrier

    const bf16* const wQ = hqkvf + h * 4096;            // pre-scaled
    const bf16* const wK = hqkvf + 16384 + h * 4096;
    const bf16* const wV = hqkvf + 32768 + h * 4096;

    bf16x8 qf[4], kf[4];

    // ---- Q^T = (S*Wq) @ X^T, bias via C-init ----
    {
        const float4 b0 = *(const float4*)(qkv_b + h*32 + hi*8);
        const float4 b1 = *(const float4*)(qkv_b + h*32 + hi*8 + 4);
        const f32x4 c0 = f4ofs(b0, SCALE);
        const f32x4 c1 = f4ofs(b1, SCALE);
        f32x4 acc[2][4];
        #pragma unroll
        for (int n = 0; n < 4; ++n) { acc[0][n] = c0; acc[1][n] = c1; }
        #pragma unroll
        for (int kb = 0; kb < 4; ++kb) {
            bf16x8 xf[4];
            #pragma unroll
            for (int n = 0; n < 4; ++n) {
                const int row = n*16 + lo;
                xf[n] = *(const bf16x8*)(sX + row*256 + ((kb*64 + hi*16) ^ SW(row)));
            }
            const bf16x8 w0 = *(const bf16x8*)(wQ + (kb*2    )*512 + lane*8);
            const bf16x8 w1 = *(const bf16x8*)(wQ + (kb*2 + 1)*512 + lane*8);
            #pragma unroll
            for (int n = 0; n < 4; ++n) {
                acc[0][n] = MFMA(w0, xf[n], acc[0][n]);
                acc[1][n] = MFMA(w1, xf[n], acc[1][n]);
            }
        }
        #pragma unroll
        for (int n = 0; n < 4; ++n)
            qf[n] = cat8(pk4(acc[0][n]), pk4(acc[1][n]));
    }

    // ---- K^T only (A-frags, token-permuted rows), bias via C-init ----
    {
        const float4 k0 = *(const float4*)(qkv_b + 128 + h*32 + hi*8);
        const float4 k1 = *(const float4*)(qkv_b + 128 + h*32 + hi*8 + 4);
        const f32x4 ck0 = f4of(k0), ck1 = f4of(k1);
        f32x4 ak[2][4];
        #pragma unroll
        for (int m = 0; m < 4; ++m) { ak[0][m] = ck0; ak[1][m] = ck1; }
        #pragma unroll
        for (int kb = 0; kb < 4; ++kb) {
            bf16x8 xf[4];
            #pragma unroll
            for (int m = 0; m < 4; ++m) {
                const int row = (m >> 1)*32 + (m & 1)*4 + prow;
                xf[m] = *(const bf16x8*)(sX + row*256 + ((kb*64 + hi*16) ^ SW(row)));
            }
            const bf16x8 wk0 = *(const bf16x8*)(wK + (kb*2    )*512 + lane*8);
            const bf16x8 wk1 = *(const bf16x8*)(wK + (kb*2 + 1)*512 + lane*8);
            #pragma unroll
            for (int m = 0; m < 4; ++m) {
                ak[0][m] = MFMA(wk0, xf[m], ak[0][m]);
                ak[1][m] = MFMA(wk1, xf[m], ak[1][m]);
            }
        }
        #pragma unroll
        for (int m = 0; m < 4; ++m)
            kf[m] = cat8(pk4(ak[0][m]), pk4(ak[1][m]));
    }

    // ---- S^T = K @ Q^T + (bias+mask as C-init); softmax (no max-sub) ----
    const bool ey = (wy == 23), ex = (wx == 23);
    const bool edge = ey || ex;
    const float* const wbh = wbf + h * 4096;
    bf16x8 pf[2][4];
    float rinv[4];
    #pragma unroll
    for (int n = 0; n < 4; ++n) {
        const int i_ = n*16 + lo;
        const int yi = i_ >> 3, xi = i_ & 7;
        const int ri = (ey ? (yi < 4 ? 1 : 2) : 0) * 3 + (ex ? (xi < 4 ? 1 : 2) : 0);
        f32x4 sc[4];
        #pragma unroll
        for (int m = 0; m < 4; ++m) {
            f32x4 ci = *(const f32x4*)(wbh + (n*4 + m)*256 + lane*4);
            if (edge) {
                #pragma unroll
                for (int r = 0; r < 4; ++r) {
                    const int j_ = (m >> 1)*32 + hi*8 + (m & 1)*4 + r;
                    const int yj = j_ >> 3, xj = j_ & 7;
                    const int rj = (ey ? (yj < 4 ? 1 : 2) : 0) * 3 + (ex ? (xj < 4 ? 1 : 2) : 0);
                    ci[r] += (ri != rj) ? -100.0f : 0.0f;
                }
            }
            sc[m] = MFMA(kf[m], qf[n], ci);
        }
        float sum = 0.f;
        #pragma unroll
        for (int m = 0; m < 4; ++m)
            #pragma unroll
            for (int r = 0; r < 4; ++r) {
                const float p = __expf(sc[m][r]);
                sc[m][r] = p; sum += p;
            }
        sum += __shfl_xor(sum, 16);
        sum += __shfl_xor(sum, 32);
        rinv[n] = 1.0f / sum;
        pf[0][n] = cat8(pk4(sc[0]), pk4(sc[1]));
        pf[1][n] = cat8(pk4(sc[2]), pk4(sc[3]));
    }

    // ---- V fused with PV, one output-half at a time (low accum pressure) ----
    bf16* const ob = obuf + (size_t)bid * 8192 + h * 2048;
    #pragma unroll
    for (int o = 0; o < 2; ++o) {
        const float bv = qkv_b[256 + h*32 + o*16 + lo];
        const f32x4 cv = splat4(bv);
        f32x4 av[4];
        #pragma unroll
        for (int m = 0; m < 4; ++m) av[m] = cv;
        #pragma unroll
        for (int kb = 0; kb < 4; ++kb) {
            bf16x8 xf[4];
            #pragma unroll
            for (int m = 0; m < 4; ++m) {
                const int row = (m >> 1)*32 + (m & 1)*4 + prow;
                xf[m] = *(const bf16x8*)(sX + row*256 + ((kb*64 + hi*16) ^ SW(row)));
            }
            const bf16x8 wv = *(const bf16x8*)(wV + (kb*2 + o)*512 + lane*8);
            #pragma unroll
            for (int m = 0; m < 4; ++m)
                av[m] = MFMA(xf[m], wv, av[m]);
        }
        bf16x8 vf[2];
        #pragma unroll
        for (int kb = 0; kb < 2; ++kb)
            vf[kb] = cat8(pk4(av[kb*2]), pk4(av[kb*2 + 1]));

        f32x4 o0[4];
        #pragma unroll
        for (int n = 0; n < 4; ++n) { o0[n][0]=0.f; o0[n][1]=0.f; o0[n][2]=0.f; o0[n][3]=0.f; }
        #pragma unroll
        for (int kb = 0; kb < 2; ++kb)
            #pragma unroll
            for (int n = 0; n < 4; ++n)
                o0[n] = MFMA(vf[kb], pf[kb][n], o0[n]);

        #pragma unroll
        for (int n = 0; n < 4; ++n)
            *(bf16x4*)(ob + (n*2 + o)*256 + lane*4) = pk4s(o0[n], rinv[n]);
    }
}

// ---------------------------------------------------------------------------
// Projection by image rows.
// ---------------------------------------------------------------------------
__global__ __launch_bounds__(512, 3)
void proj_rows(const bf16* __restrict__ obuf, const bf16* __restrict__ hprojf,
               const float* __restrict__ proj_b, float* __restrict__ out)
{
    __shared__ char sR[49152];   // [192 tok][256B bf16], col ^ SW(tok)
    const int tid  = threadIdx.x;
    const int lane = tid & 63;
    const int wv   = tid >> 6;
    const int lo   = lane & 15;
    const int hi   = lane >> 4;

    const int bid   = blockIdx.x;        // 1536 = 8 batch x 192 rows
    const int batch = bid & 7;
    const int hh    = bid >> 3;          // output row 0..191
    int hr = hh + 188; if (hr >= 192) hr -= 192;   // rolled-frame row
    const int wy = hr >> 3, iy = hr & 7;
    const int n_ = iy >> 1;

    #pragma unroll
    for (int k = 0; k < 6; ++k) {
        const int i  = tid + k*512;      // 0..3071
        const int wr = i >> 4;           // rolled-frame col
        const int cc = i & 15;           // 8-channel chunk
        const int wxx = wr >> 3, ix = wr & 7;
        const int win = (wy*NWX + wxx)*8 + batch;
        const int lo2 = (iy & 1)*8 + ix;
        const int hg = cc >> 2, oo = (cc >> 1) & 1, hp = cc & 1;
        const bf16* bp = obuf + (size_t)win*8192 + hg*2048 + (n_*2 + oo)*256;
        const bf16x4 p0 = *(const bf16x4*)(bp + ((hp*2    )*16 + lo2)*4);
        const bf16x4 p1 = *(const bf16x4*)(bp + ((hp*2 + 1)*16 + lo2)*4);
        int wo = wr + 4; if (wo >= 192) wo -= 192;
        *(bf16x8*)(sR + wo*256 + ((cc*16) ^ SW(wo))) = cat8(p0, p1);
    }
    __syncthreads();

    const int q  = wv >> 1;
    const int oh = wv & 1;
    const f32x4 FZ = {0.f, 0.f, 0.f, 0.f};
    f32x4 acc[4][3];
    #pragma unroll
    for (int tA = 0; tA < 4; ++tA)
        #pragma unroll
        for (int tN = 0; tN < 3; ++tN) acc[tA][tN] = FZ;

    #pragma unroll
    for (int kb = 0; kb < 4; ++kb) {
        bf16x8 of[3];
        #pragma unroll
        for (int tN = 0; tN < 3; ++tN) {
            const int tok = q*48 + tN*16 + lo;
            of[tN] = *(const bf16x8*)(sR + tok*256 + ((kb*64 + hi*16) ^ SW(tok)));
        }
        bf16x8 wf[4];
        #pragma unroll
        for (int tA = 0; tA < 4; ++tA)
            wf[tA] = *(const bf16x8*)(hprojf + (size_t)(((oh*4 + kb)*4 + tA)*64 + lane)*8);
        #pragma unroll
        for (int tA = 0; tA < 4; ++tA)
            #pragma unroll
            for (int tN = 0; tN < 3; ++tN)
                acc[tA][tN] = MFMA(of[tN], wf[tA], acc[tA][tN]);
    }

    #pragma unroll
    for (int tA = 0; tA < 4; ++tA) {
        const int oc = oh*64 + tA*16 + lo;
        const float pb = proj_b[oc];
        float* const orow = out + (size_t)(batch*128 + oc) * HWSZ + hh*HIMG;
        #pragma unroll
        for (int tN = 0; tN < 3; ++tN) {
            const int tb = q*48 + tN*16 + hi*4;
            float4 v;
            v.x = acc[tA][tN][0] + pb;
            v.y = acc[tA][tN][1] + pb;
            v.z = acc[tA][tN][2] + pb;
            v.w = acc[tA][tN][3] + pb;
            *(float4*)(orow + tb) = v;
        }
    }
}

// ---------------------------------------------------------------------------
// Fallback: straightforward fp32 reference path (no workspace needed).
// ---------------------------------------------------------------------------
__global__ __launch_bounds__(64)
void swin_ref(const float* __restrict__ x, const float* __restrict__ qkv_w,
              const float* __restrict__ qkv_b, const float* __restrict__ proj_w,
              const float* __restrict__ proj_b, const float* __restrict__ rpb,
              float* __restrict__ out)
{
    const int bid   = blockIdx.x;
    const int batch = bid & 7;
    const int wrem  = bid >> 3;
    const int wy    = wrem / NWX;
    const int wx    = wrem - wy * NWX;
    const int t     = threadIdx.x;       // token in window
    const int iy = t >> 3, ix = t & 7;
    const bool ey = (wy == 23), ex = (wx == 23);

    __shared__ float sxw[64][128];
    __shared__ float sq[64][128], sk[64][128], sv[64][128], so[64][128];

    int hh = wy*8 + iy + 4; if (hh >= HIMG) hh -= HIMG;
    int ww = wx*8 + ix + 4; if (ww >= HIMG) ww -= HIMG;
    const float* xp = x + (size_t)batch*128*HWSZ + hh*HIMG + ww;
    for (int c = 0; c < 128; ++c) sxw[t][c] = xp[(size_t)c*HWSZ];
    __syncthreads();

    for (int d = 0; d < 128; ++d) {
        float aq = qkv_b[d], ak2 = qkv_b[128 + d], av2 = qkv_b[256 + d];
        for (int c = 0; c < 128; ++c) {
            const float xv = sxw[t][c];
            aq  += qkv_w[d*128 + c] * xv;
            ak2 += qkv_w[(128 + d)*128 + c] * xv;
            av2 += qkv_w[(256 + d)*128 + c] * xv;
        }
        sq[t][d] = aq; sk[t][d] = ak2; sv[t][d] = av2;
    }
    __syncthreads();

    const float SCALE = 0.17677669529663687f;
    const int ri = (ey ? (iy < 4 ? 1 : 2) : 0) * 3 + (ex ? (ix < 4 ? 1 : 2) : 0);
    for (int h = 0; h < 4; ++h) {
        float p[64];
        float mx = -1e30f;
        for (int j = 0; j < 64; ++j) {
            const int yj = j >> 3, xj = j & 7;
            float s = 0.f;
            for (int d = 0; d < 32; ++d)
                s += sq[t][h*32 + d] * sk[j][h*32 + d];
            s = s * SCALE + rpb[((iy - yj + 7)*15 + (ix - xj + 7))*4 + h];
            const int rj = (ey ? (yj < 4 ? 1 : 2) : 0) * 3 + (ex ? (xj < 4 ? 1 : 2) : 0);
            if (ri != rj) s -= 100.0f;
            p[j] = s; mx = fmaxf(mx, s);
        }
        float sum = 0.f;
        for (int j = 0; j < 64; ++j) { p[j] = __expf(p[j] - mx); sum += p[j]; }
        const float inv = 1.0f / sum;
        for (int d = 0; d < 32; ++d) {
            float o = 0.f;
            for (int j = 0; j < 64; ++j) o += p[j] * sv[j][h*32 + d];
            so[t][h*32 + d] = o * inv;
        }
    }
    __syncthreads();

    for (int d = 0; d < 128; ++d) {
        float a = proj_b[d];
        for (int c = 0; c < 128; ++c) a += proj_w[d*128 + c] * so[t][c];
        out[(size_t)(batch*128 + d)*HWSZ + hh*HIMG + ww] = a;
    }
}

extern "C" void kernel_launch(void* const* d_in, const int* in_sizes, int n_in,
                              void* d_out, int out_size, void* d_ws, size_t ws_size,
                              hipStream_t stream) {
    const float* x      = (const float*)d_in[0];
    const float* qkv_w  = (const float*)d_in[1];
    const float* qkv_b  = (const float*)d_in[2];
    const float* proj_w = (const float*)d_in[3];
    const float* proj_b = (const float*)d_in[4];
    const float* rpb    = (const float*)d_in[5];
    float* out = (float*)d_out;

    // ws bytes: [0,64K) wbias f32 | [64K,160K) hqkv | [160K,192K) hproj
    //           [192K,256K) wbf f32 | [256K,352K) hqkvf | [352K,384K) hprojf
    //           [384K, +75.5M) obuf
    const size_t SETUP = 393216;
    const size_t OSZ   = (size_t)4608 * 16384;

    float* wbias = (float*)d_ws;
    bf16*  hqkv  = (bf16*)((char*)d_ws + 65536);
    bf16*  hproj = (bf16*)((char*)d_ws + 163840);
    float* wbf   = (float*)((char*)d_ws + 196608);
    bf16*  hqkvf = (bf16*)((char*)d_ws + 262144);
    bf16*  hprojf= (bf16*)((char*)d_ws + 360448);
    bf16*  obuf  = (bf16*)((char*)d_ws + SETUP);

    if (ws_size >= SETUP + OSZ) {
        setup_ws<<<640, 256, 0, stream>>>(rpb, qkv_w, proj_w, wbias, hqkv, hproj,
                                          wbf, hqkvf, hprojf);
        qkv_attn<<<4608, 256, 0, stream>>>(x, qkv_b, hqkvf, wbf, obuf);
        proj_rows<<<1536, 512, 0, stream>>>(obuf, hprojf, proj_b, out);
    } else {
        swin_ref<<<4608, 64, 0, stream>>>(x, qkv_w, qkv_b, proj_w, proj_b, rpb, out);
    }
}